// Round 5
// baseline (1685.377 us; speedup 1.0000x reference)
//
#include <hip/hip_runtime.h>
#include <math.h>

typedef _Float16 half_t;
typedef __attribute__((ext_vector_type(2))) _Float16 half2_t;
typedef __attribute__((ext_vector_type(4))) _Float16 half4;

// ---- problem constants --------------------------------------------------
constexpr int kB   = 32;
constexpr int kN   = 512;
constexpr int kM   = 32;
constexpr int kHA  = 64;
constexpr int kHB  = 101;
constexpr int kHO  = 128;            // 2*H_A
constexpr int kNF  = 229;            // 2*H_A + H_B
constexpr int kRows = kB * kN;       // 16384 (b,n) pairs
constexpr long kTRows = (long)kRows * kM;   // 524288 gated rows
constexpr int kNCls = 10;
constexpr float kEps = 1e-5f;
// stats/apply geometry: 16 pairs/block, thread = (pair, 4 perm channels), all 32 m in-thread
constexpr int kGP   = 16;            // pairs per block
constexpr int kNBs  = kRows / kGP;   // 1024 blocks (divisible by 8 XCDs)
constexpr int kT    = 512;           // threads per block
constexpr int kTaps = 8;             // contiguous Gaussian window (err ~1e-8)

// perm channel j (0..127) -> original channel. j=4*cg+e maps to
// {2cg, 64+2cg, 2cg+1, 64+2cg+1} so each thread's float4 holds 2 filt/core pairs.
__device__ __forceinline__ int origCh(int j) {
    return ((j & 1) << 6) + ((j >> 2) << 1) + ((j >> 1) & 1);
}

// ---- kernel 0: broadcast atom embeddings --------------------------------
__global__ void k_init_atom(const float* __restrict__ emb, float* __restrict__ atom) {
    int i = blockIdx.x * blockDim.x + threadIdx.x;
    atom[i] = emb[i & (kN * kHA - 1)];
}

// ---- kernel 1: (resid+relu) then preA/preB GEMMs (PERMUTED channel out) --
// Block 0 also zeroes bn1acc (256 f) and this layer's BN2 accumulator (128 f).
template<bool RESID>
__global__ __launch_bounds__(256)
void k_pre(const float* __restrict__ atomIn, float* __restrict__ atomOut,
           const float* __restrict__ summed, const float* __restrict__ acc2,
           const float* __restrict__ g2, const float* __restrict__ b2,
           const float* __restrict__ W, const float* __restrict__ bias,
           float* __restrict__ preA, float* __restrict__ preB,
           float* __restrict__ bn1acc, float* __restrict__ zeroBuf) {
    __shared__ float sA[32 * 64];
    __shared__ float sc2s[128];
    int t = threadIdx.x;
    if (blockIdx.x == 0) {
        bn1acc[t] = 0.f;
        if (t < 128) zeroBuf[t] = 0.f;
    }
    if (RESID) {
        if (t < 64) {
            float inv = 1.f / (float)kRows;
            float mu = acc2[t] * inv;
            float var = acc2[64 + t] * inv - mu * mu;
            float sc = g2[t] * rsqrtf(var + kEps);
            sc2s[t] = sc;
            sc2s[64 + t] = b2[t] - mu * sc;
        }
        __syncthreads();
    }
    int r0 = blockIdx.x * 32;
    for (int i = t; i < 32 * 64; i += 256) {
        float v = atomIn[r0 * 64 + i];
        if (RESID) {
            int h = i & 63;
            v = fmaxf(v + fmaf(summed[r0 * 64 + i], sc2s[h], sc2s[64 + h]), 0.f);
            atomOut[r0 * 64 + i] = v;
        }
        sA[i] = v;
    }
    __syncthreads();
    int cg = t & 31, rg = t >> 5;
    float2 bb01 = *(const float2*)&bias[2 * cg];
    float2 bb23 = *(const float2*)&bias[64 + 2 * cg];
    float4 accA[4], accB[4];
    #pragma unroll
    for (int r = 0; r < 4; ++r) {
        accA[r] = make_float4(bb01.x, bb23.x, bb01.y, bb23.y);
        accB[r] = make_float4(0.f, 0.f, 0.f, 0.f);
    }
    for (int k = 0; k < 64; ++k) {
        float2 wA01 = *(const float2*)&W[k * kHO + 2 * cg];
        float2 wA23 = *(const float2*)&W[k * kHO + 64 + 2 * cg];
        float2 wB01 = *(const float2*)&W[(64 + k) * kHO + 2 * cg];
        float2 wB23 = *(const float2*)&W[(64 + k) * kHO + 64 + 2 * cg];
        #pragma unroll
        for (int r = 0; r < 4; ++r) {
            float a = sA[(rg * 4 + r) * 64 + k];
            accA[r].x = fmaf(a, wA01.x, accA[r].x);
            accA[r].y = fmaf(a, wA23.x, accA[r].y);
            accA[r].z = fmaf(a, wA01.y, accA[r].z);
            accA[r].w = fmaf(a, wA23.y, accA[r].w);
            accB[r].x = fmaf(a, wB01.x, accB[r].x);
            accB[r].y = fmaf(a, wB23.x, accB[r].y);
            accB[r].z = fmaf(a, wB01.y, accB[r].z);
            accB[r].w = fmaf(a, wB23.y, accB[r].w);
        }
    }
    #pragma unroll
    for (int r = 0; r < 4; ++r) {
        int row = r0 + rg * 4 + r;
        *(float4*)&preA[row * kHO + 4 * cg] = accA[r];
        *(float4*)&preB[row * kHO + 4 * cg] = accB[r];
    }
}

// ---- shared staging: W3 (fp16, perm layout) + per-(pair,m) window/gather --
__device__ __forceinline__ void stage_w3_and_tiles(int t, int lb,
        const float* __restrict__ dist, const int* __restrict__ nbrs,
        const float* __restrict__ W3, half_t* __restrict__ W3h,
        float (*wv)[kM][kTaps], int2 (*rw)[kM]) {
    for (int i = t; i < kHB * 64; i += kT) {       // half2-packed stage
        int row = i >> 6, pj = (i & 63) * 2;
        half2_t hp;
        hp.x = (half_t)W3[row * kHO + origCh(pj)];
        hp.y = (half_t)W3[row * kHO + origCh(pj + 1)];
        *(half2_t*)&W3h[row * 128 + pj] = hp;
    }
    // t = lp*32 + m  (512 threads cover all (pair, m))
    int lp = t >> 5, m = t & 31;
    int p = lb * kGP + lp;
    float d = dist[p * kM + m];
    int kc = (int)floorf(d * 10.f);
    int ks = min(max(kc - 3, 0), kHB - kTaps);
    int ro = ((p & ~(kN - 1)) + nbrs[p * kM + m]) * kHO;
    rw[lp][m] = make_int2(ro, ks * kHO);
    #pragma unroll
    for (int j = 0; j < kTaps; ++j) {
        float dd = d - 0.1f * (float)(ks + j);
        wv[lp][m][j] = __expf(-100.f * dd * dd);
    }
}

// ---- kernel 2: BN1 stats; atomic per-channel S/SS into bn1acc (perm) -----
__global__ __launch_bounds__(kT, 5)
void k_stats(const float* __restrict__ dist, const int* __restrict__ nbrs,
             const float* __restrict__ preA, const float* __restrict__ preB,
             const float* __restrict__ W3, float* __restrict__ acc) {
    __shared__ half_t W3h[kHB * kHO];      // 25856 B
    __shared__ float wv[kGP][kM][kTaps];   // 16384 B (aliased as red after loop)
    __shared__ int2  rw[kGP][kM];          // 4096 B
    int t = threadIdx.x;
    int lb = (int)(blockIdx.x & 7) * (kNBs / 8) + (int)(blockIdx.x >> 3);
    stage_w3_and_tiles(t, lb, dist, nbrs, W3, W3h, wv, rw);
    __syncthreads();
    int cg = t & 31, lp = t >> 5;
    int p = lb * kGP + lp;
    float4 pa = *(const float4*)&preA[(size_t)p * kHO + 4 * cg];
    float S0 = 0.f, S1 = 0.f, S2 = 0.f, S3 = 0.f;
    float T0 = 0.f, T1 = 0.f, T2 = 0.f, T3 = 0.f;
    for (int m0 = 0; m0 < kM; m0 += 4) {
        int2 rwl[4];
        float4 pb[4];
        #pragma unroll
        for (int u = 0; u < 4; ++u) rwl[u] = rw[lp][m0 + u];
        #pragma unroll
        for (int u = 0; u < 4; ++u)
            pb[u] = *(const float4*)&preB[(size_t)rwl[u].x + 4 * cg];
        #pragma unroll
        for (int u = 0; u < 4; ++u) {
            float4 w04 = *(const float4*)&wv[lp][m0 + u][0];
            float4 w48 = *(const float4*)&wv[lp][m0 + u][4];
            float warr[kTaps] = {w04.x, w04.y, w04.z, w04.w,
                                 w48.x, w48.y, w48.z, w48.w};
            float x0 = pa.x + pb[u].x, x1 = pa.y + pb[u].y;
            float x2 = pa.z + pb[u].z, x3 = pa.w + pb[u].w;
            const half_t* hb = &W3h[rwl[u].y + 4 * cg];
            #pragma unroll
            for (int j = 0; j < kTaps; ++j) {
                half4 hv = *(const half4*)&hb[j * kHO];
                float w = warr[j];
                x0 = fmaf(w, (float)hv.x, x0);
                x1 = fmaf(w, (float)hv.y, x1);
                x2 = fmaf(w, (float)hv.z, x2);
                x3 = fmaf(w, (float)hv.w, x3);
            }
            S0 += x0; S1 += x1; S2 += x2; S3 += x3;
            T0 = fmaf(x0, x0, T0); T1 = fmaf(x1, x1, T1);
            T2 = fmaf(x2, x2, T2); T3 = fmaf(x3, x3, T3);
        }
    }
    float* red = (float*)wv;               // 16*128 floats, wv is dead now
    __syncthreads();
    *(float4*)&red[lp * 128 + 4 * cg] = make_float4(S0, S1, S2, S3);
    __syncthreads();
    if (t < 128) {
        float s = 0.f;
        #pragma unroll
        for (int l2 = 0; l2 < kGP; ++l2) s += red[l2 * 128 + t];
        atomicAdd(&acc[t], s);
    }
    __syncthreads();
    *(float4*)&red[lp * 128 + 4 * cg] = make_float4(T0, T1, T2, T3);
    __syncthreads();
    if (t < 128) {
        float s = 0.f;
        #pragma unroll
        for (int l2 = 0; l2 < kGP; ++l2) s += red[l2 * 128 + t];
        atomicAdd(&acc[128 + t], s);
    }
}

// ---- kernel 3: BN1 inline, sigmoid*relu, in-thread sum over m ------------
__global__ __launch_bounds__(kT, 5)
void k_apply(const float* __restrict__ dist, const int* __restrict__ nbrs,
             const float* __restrict__ preA, const float* __restrict__ preB,
             const float* __restrict__ W3, const float* __restrict__ acc,
             const float* __restrict__ g1, const float* __restrict__ b1,
             float* __restrict__ summed, float* __restrict__ acc2) {
    __shared__ half_t W3h[kHB * kHO];
    __shared__ float wv[kGP][kM][kTaps];   // aliased as red after loop
    __shared__ int2  rw[kGP][kM];
    __shared__ float scP[128], shP[128];
    int t = threadIdx.x;
    int lb = (int)(blockIdx.x & 7) * (kNBs / 8) + (int)(blockIdx.x >> 3);
    stage_w3_and_tiles(t, lb, dist, nbrs, W3, W3h, wv, rw);
    if (t < 128) {                         // BN1 scale/shift (perm order)
        float inv = 1.f / (float)kTRows;
        int oc = origCh(t);
        float mu = acc[t] * inv;
        float var = acc[128 + t] * inv - mu * mu;
        float sc = g1[oc] * rsqrtf(var + kEps);
        scP[t] = sc;
        shP[t] = b1[oc] - mu * sc;
    }
    __syncthreads();
    int cg = t & 31, lp = t >> 5;
    int p = lb * kGP + lp;
    float4 pa = *(const float4*)&preA[(size_t)p * kHO + 4 * cg];
    float4 sc4 = *(const float4*)&scP[4 * cg];
    float4 sh4 = *(const float4*)&shP[4 * cg];
    float s0 = 0.f, s1 = 0.f;
    for (int m0 = 0; m0 < kM; m0 += 4) {
        int2 rwl[4];
        float4 pb[4];
        #pragma unroll
        for (int u = 0; u < 4; ++u) rwl[u] = rw[lp][m0 + u];
        #pragma unroll
        for (int u = 0; u < 4; ++u)
            pb[u] = *(const float4*)&preB[(size_t)rwl[u].x + 4 * cg];
        #pragma unroll
        for (int u = 0; u < 4; ++u) {
            float4 w04 = *(const float4*)&wv[lp][m0 + u][0];
            float4 w48 = *(const float4*)&wv[lp][m0 + u][4];
            float warr[kTaps] = {w04.x, w04.y, w04.z, w04.w,
                                 w48.x, w48.y, w48.z, w48.w};
            float x0 = pa.x + pb[u].x, x1 = pa.y + pb[u].y;
            float x2 = pa.z + pb[u].z, x3 = pa.w + pb[u].w;
            const half_t* hb = &W3h[rwl[u].y + 4 * cg];
            #pragma unroll
            for (int j = 0; j < kTaps; ++j) {
                half4 hv = *(const half4*)&hb[j * kHO];
                float w = warr[j];
                x0 = fmaf(w, (float)hv.x, x0);
                x1 = fmaf(w, (float)hv.y, x1);
                x2 = fmaf(w, (float)hv.z, x2);
                x3 = fmaf(w, (float)hv.w, x3);
            }
            float yf0 = fmaf(x0, sc4.x, sh4.x);
            float yc0 = fmaf(x1, sc4.y, sh4.y);
            float yf1 = fmaf(x2, sc4.z, sh4.z);
            float yc1 = fmaf(x3, sc4.w, sh4.w);
            float sg0 = 1.f / (1.f + __expf(-yf0));
            float sg1 = 1.f / (1.f + __expf(-yf1));
            s0 = fmaf(sg0, fmaxf(yc0, 0.f), s0);
            s1 = fmaf(sg1, fmaxf(yc1, 0.f), s1);
        }
    }
    // summed channels (2cg, 2cg+1) of pair p — direct store, no reduction
    *(float2*)&summed[(size_t)p * kHA + 2 * cg] = make_float2(s0, s1);
    // BN2 partials: one LDS round-trip at kernel end
    float* red = (float*)wv;
    __syncthreads();
    *(float2*)&red[lp * 64 + 2 * cg] = make_float2(s0, s1);
    __syncthreads();
    if (t < 64) {
        float S2 = 0.f, SS2 = 0.f;
        #pragma unroll
        for (int l2 = 0; l2 < kGP; ++l2) {
            float v = red[l2 * 64 + t];
            S2 += v;
            SS2 = fmaf(v, v, SS2);
        }
        atomicAdd(&acc2[t], S2);
        atomicAdd(&acc2[64 + t], SS2);
    }
}

// ---- kernel F: inline BN2, resid + pool + classifier + softmax -----------
__global__ __launch_bounds__(1024)
void k_final(const float* __restrict__ atom, const float* __restrict__ summed,
             const float* __restrict__ acc2, const float* __restrict__ g2,
             const float* __restrict__ b2, const float* __restrict__ cw,
             const float* __restrict__ cb, float* __restrict__ out) {
    __shared__ float red[1024];
    __shared__ float sc2s[128];
    __shared__ float pooled[kHA];
    __shared__ float lg[kNCls];
    int b = blockIdx.x, t = threadIdx.x;
    if (t < 64) {
        float inv = 1.f / (float)kRows;
        float mu = acc2[t] * inv;
        float var = acc2[64 + t] * inv - mu * mu;
        float sc = g2[t] * rsqrtf(var + kEps);
        sc2s[t] = sc;
        sc2s[64 + t] = b2[t] - mu * sc;
    }
    __syncthreads();
    int h = t & 63, q = t >> 6;
    const float* ab = atom + (long)b * kN * kHA;
    const float* sb = summed + (long)b * kN * kHA;
    float scv = sc2s[h], shv = sc2s[64 + h];
    float s = 0.f;
    for (int n = q * 32; n < q * 32 + 32; ++n) {
        float v = ab[n * 64 + h] + fmaf(sb[n * 64 + h], scv, shv);
        s += fmaxf(v, 0.f);
    }
    red[t] = s;
    __syncthreads();
    if (t < 64) {
        float v = 0.f;
        #pragma unroll
        for (int qq = 0; qq < 16; ++qq) v += red[qq * 64 + t];
        pooled[t] = v * (1.f / kN);
    }
    __syncthreads();
    if (t < kNCls) {
        float a = cb[t];
        #pragma unroll
        for (int k = 0; k < kHA; ++k) a = fmaf(pooled[k], cw[k * kNCls + t], a);
        lg[t] = a;
    }
    __syncthreads();
    if (t == 0) {
        float mx = lg[0];
        for (int c = 1; c < kNCls; ++c) mx = fmaxf(mx, lg[c]);
        float e[kNCls], se = 0.f;
        for (int c = 0; c < kNCls; ++c) { e[c] = __expf(lg[c] - mx); se += e[c]; }
        float inv = 1.f / se;
        for (int c = 0; c < kNCls; ++c) out[b * kNCls + c] = e[c] * inv;
    }
}

// ---- launcher ------------------------------------------------------------
extern "C" void kernel_launch(void* const* d_in, const int* in_sizes, int n_in,
                              void* d_out, int out_size, void* d_ws, size_t ws_size,
                              hipStream_t stream) {
    const float* dist = (const float*)d_in[0];
    const int*   nbrs = (const int*)d_in[1];
    const float* emb  = (const float*)d_in[2];
    const float* fcw  = (const float*)d_in[3];
    const float* fcb  = (const float*)d_in[4];
    const float* bn1g = (const float*)d_in[5];
    const float* bn1b = (const float*)d_in[6];
    const float* bn2g = (const float*)d_in[7];
    const float* bn2b = (const float*)d_in[8];
    const float* clw  = (const float*)d_in[9];
    const float* clb  = (const float*)d_in[10];
    float* out = (float*)d_out;

    float* ws     = (float*)d_ws;
    float* atom   = ws;                          // kRows*kHA
    float* preA   = atom + kRows * kHA;          // kRows*kHO (perm)
    float* preB   = preA + kRows * kHO;          // kRows*kHO (perm)
    float* summed = preB + kRows * kHO;          // kRows*kHA
    float* bn1acc = summed + kRows * kHA;        // 256 (S perm | SS perm)
    float* acc2a  = bn1acc + 256;                // 128 (BN2 S|SS, even layers)
    float* acc2b  = acc2a + 128;                 // 128 (odd layers)

    k_init_atom<<<dim3(kRows * kHA / 256), dim3(256), 0, stream>>>(emb, atom);
    for (int l = 0; l < 4; ++l) {
        const float* W  = fcw + (long)l * kNF * kHO;
        const float* W3 = W + 2 * kHA * kHO;
        float* accW = (l & 1) ? acc2b : acc2a;
        float* accR = ((l - 1) & 1) ? acc2b : acc2a;
        if (l == 0)
            k_pre<false><<<dim3(kRows / 32), dim3(256), 0, stream>>>(
                atom, atom, nullptr, nullptr, nullptr, nullptr,
                W, fcb + l * kHO, preA, preB, bn1acc, accW);
        else
            k_pre<true><<<dim3(kRows / 32), dim3(256), 0, stream>>>(
                atom, atom, summed, accR, bn2g + (l - 1) * kHA, bn2b + (l - 1) * kHA,
                W, fcb + l * kHO, preA, preB, bn1acc, accW);
        k_stats<<<dim3(kNBs), dim3(kT), 0, stream>>>(dist, nbrs, preA, preB, W3, bn1acc);
        k_apply<<<dim3(kNBs), dim3(kT), 0, stream>>>(dist, nbrs, preA, preB, W3, bn1acc,
                                                     bn1g + l * kHO, bn1b + l * kHO,
                                                     summed, accW);
    }
    k_final<<<dim3(kB), dim3(1024), 0, stream>>>(atom, summed, acc2b,
                                                 bn2g + 3 * kHA, bn2b + 3 * kHA,
                                                 clw, clb, out);
}

// Round 6
// 727.685 us; speedup vs baseline: 2.3161x; 2.3161x over previous
//
#include <hip/hip_runtime.h>
#include <math.h>

typedef _Float16 half_t;
typedef __attribute__((ext_vector_type(4))) _Float16 half4;

// ---- problem constants --------------------------------------------------
constexpr int kB   = 32;
constexpr int kN   = 512;
constexpr int kM   = 32;
constexpr int kHA  = 64;
constexpr int kHB  = 101;
constexpr int kHO  = 128;            // 2*H_A
constexpr int kNF  = 229;            // 2*H_A + H_B
constexpr int kRows = kB * kN;       // 16384 (b,n) pairs
constexpr long kTRows = (long)kRows * kM;   // 524288 gated rows
constexpr int kNCls = 10;
constexpr float kEps = 1e-5f;
// stats/apply geometry (round-4 proven): 8 pairs/block, 2048 blocks
constexpr int kG    = 8;             // pairs per block
constexpr int kNB   = kRows / kG;    // 2048 blocks (divisible by 8 XCDs)
constexpr int kT    = 512;           // threads per block
constexpr int kTaps = 8;             // contiguous Gaussian window (err ~1e-8)

// perm channel j (0..127) -> original channel. j=4*cg+e maps to
// {2cg, 64+2cg, 2cg+1, 64+2cg+1} so each thread's float4 holds 2 filt/core pairs.
__device__ __forceinline__ int origCh(int j) {
    return ((j & 1) << 6) + ((j >> 2) << 1) + ((j >> 1) & 1);
}

// ---- kernel 0: broadcast atom embeddings --------------------------------
__global__ void k_init_atom(const float* __restrict__ emb, float* __restrict__ atom) {
    int i = blockIdx.x * blockDim.x + threadIdx.x;
    atom[i] = emb[i & (kN * kHA - 1)];
}

// ---- kernel 1: (resid+relu) then preA/preB GEMMs (PERMUTED channel out) --
// Block 0 also zeroes bn1acc (256 f) and this layer's BN2 accumulator (128 f).
template<bool RESID>
__global__ __launch_bounds__(256)
void k_pre(const float* __restrict__ atomIn, float* __restrict__ atomOut,
           const float* __restrict__ summed, const float* __restrict__ acc2,
           const float* __restrict__ g2, const float* __restrict__ b2,
           const float* __restrict__ W, const float* __restrict__ bias,
           float* __restrict__ preA, float* __restrict__ preB,
           float* __restrict__ bn1acc, float* __restrict__ zeroBuf) {
    __shared__ float sA[32 * 64];
    __shared__ float sc2s[128];
    int t = threadIdx.x;
    if (blockIdx.x == 0) {
        bn1acc[t] = 0.f;
        if (t < 128) zeroBuf[t] = 0.f;
    }
    if (RESID) {
        if (t < 64) {
            float inv = 1.f / (float)kRows;
            float mu = acc2[t] * inv;
            float var = acc2[64 + t] * inv - mu * mu;
            float sc = g2[t] * rsqrtf(var + kEps);
            sc2s[t] = sc;
            sc2s[64 + t] = b2[t] - mu * sc;
        }
        __syncthreads();
    }
    int r0 = blockIdx.x * 32;
    for (int i = t; i < 32 * 64; i += 256) {
        float v = atomIn[r0 * 64 + i];
        if (RESID) {
            int h = i & 63;
            v = fmaxf(v + fmaf(summed[r0 * 64 + i], sc2s[h], sc2s[64 + h]), 0.f);
            atomOut[r0 * 64 + i] = v;
        }
        sA[i] = v;
    }
    __syncthreads();
    int cg = t & 31, rg = t >> 5;
    float2 bb01 = *(const float2*)&bias[2 * cg];
    float2 bb23 = *(const float2*)&bias[64 + 2 * cg];
    float4 accA[4], accB[4];
    #pragma unroll
    for (int r = 0; r < 4; ++r) {
        accA[r] = make_float4(bb01.x, bb23.x, bb01.y, bb23.y);
        accB[r] = make_float4(0.f, 0.f, 0.f, 0.f);
    }
    for (int k = 0; k < 64; ++k) {
        float2 wA01 = *(const float2*)&W[k * kHO + 2 * cg];
        float2 wA23 = *(const float2*)&W[k * kHO + 64 + 2 * cg];
        float2 wB01 = *(const float2*)&W[(64 + k) * kHO + 2 * cg];
        float2 wB23 = *(const float2*)&W[(64 + k) * kHO + 64 + 2 * cg];
        #pragma unroll
        for (int r = 0; r < 4; ++r) {
            float a = sA[(rg * 4 + r) * 64 + k];
            accA[r].x = fmaf(a, wA01.x, accA[r].x);
            accA[r].y = fmaf(a, wA23.x, accA[r].y);
            accA[r].z = fmaf(a, wA01.y, accA[r].z);
            accA[r].w = fmaf(a, wA23.y, accA[r].w);
            accB[r].x = fmaf(a, wB01.x, accB[r].x);
            accB[r].y = fmaf(a, wB23.x, accB[r].y);
            accB[r].z = fmaf(a, wB01.y, accB[r].z);
            accB[r].w = fmaf(a, wB23.y, accB[r].w);
        }
    }
    #pragma unroll
    for (int r = 0; r < 4; ++r) {
        int row = r0 + rg * 4 + r;
        *(float4*)&preA[row * kHO + 4 * cg] = accA[r];
        *(float4*)&preB[row * kHO + 4 * cg] = accB[r];
    }
}

// ---- kernel 2: BN1 stats; atomic per-channel S/SS into bn1acc (perm) -----
// (round-4 proven structure, unchanged)
__global__ __launch_bounds__(kT, 6)
void k_stats(const float* __restrict__ dist, const int* __restrict__ nbrs,
             const float* __restrict__ preA, const float* __restrict__ preB,
             const float* __restrict__ W3, float* __restrict__ acc) {
    __shared__ half_t W3h[kHB * kHO];      // 25856 B, perm channel order
    __shared__ float wv[kG][kM][kTaps];    // 8192 B
    __shared__ int   roff[kG][kM];         // 1024 B
    __shared__ int   wbase[kG][kM];        // 1024 B
    __shared__ float red[2048];            // 8192 B
    int t = threadIdx.x;
    int lb = (int)(blockIdx.x & 7) * (kNB / 8) + (int)(blockIdx.x >> 3);  // XCD swizzle
    for (int i = t; i < kHB * kHO; i += kT)
        W3h[i] = (half_t)W3[(i & ~127) + origCh(i & 127)];
    if (t < kG * kM) {
        int g = t >> 5, m = t & 31;
        int p = lb * kG + g;
        float d = dist[p * kM + m];
        int kc = (int)floorf(d * 10.f);
        int ks = min(max(kc - 3, 0), kHB - kTaps);
        wbase[g][m] = ks * kHO;
        roff[g][m] = (((p >> 9) << 9) + nbrs[p * kM + m]) * kHO;
        #pragma unroll
        for (int j = 0; j < kTaps; ++j) {
            float dd = d - 0.1f * (float)(ks + j);
            wv[g][m][j] = __expf(-100.f * dd * dd);
        }
    }
    __syncthreads();
    int cg = t & 31, ms = t >> 5;
    float S[4] = {0.f, 0.f, 0.f, 0.f}, SS[4] = {0.f, 0.f, 0.f, 0.f};
    for (int g = 0; g < kG; ++g) {
        int p = lb * kG + g;
        float4 pa = *(const float4*)&preA[p * kHO + 4 * cg];
        #pragma unroll
        for (int mm = 0; mm < 2; ++mm) {
            int m = ms + mm * 16;
            int ro = roff[g][m], wb = wbase[g][m];
            float4 pb = *(const float4*)&preB[ro + 4 * cg];
            float x0 = pa.x + pb.x, x1 = pa.y + pb.y;
            float x2 = pa.z + pb.z, x3 = pa.w + pb.w;
            float warr[kTaps];
            *(float4*)&warr[0] = *(const float4*)&wv[g][m][0];
            *(float4*)&warr[4] = *(const float4*)&wv[g][m][4];
            const half_t* hb = &W3h[wb + 4 * cg];
            #pragma unroll
            for (int j = 0; j < kTaps; ++j) {
                half4 hv = *(const half4*)&hb[j * kHO];
                float w = warr[j];
                x0 = fmaf(w, (float)hv.x, x0);
                x1 = fmaf(w, (float)hv.y, x1);
                x2 = fmaf(w, (float)hv.z, x2);
                x3 = fmaf(w, (float)hv.w, x3);
            }
            S[0] += x0; S[1] += x1; S[2] += x2; S[3] += x3;
            SS[0] = fmaf(x0, x0, SS[0]); SS[1] = fmaf(x1, x1, SS[1]);
            SS[2] = fmaf(x2, x2, SS[2]); SS[3] = fmaf(x3, x3, SS[3]);
        }
    }
    #pragma unroll
    for (int c = 0; c < 4; ++c) {
        S[c]  += __shfl_xor(S[c], 32);
        SS[c] += __shfl_xor(SS[c], 32);
    }
    int w = t >> 6;
    if ((t & 63) < 32) {
        *(float4*)&red[w * 128 + cg * 4] = make_float4(S[0], S[1], S[2], S[3]);
        *(float4*)&red[1024 + w * 128 + cg * 4] = make_float4(SS[0], SS[1], SS[2], SS[3]);
    }
    __syncthreads();
    if (t < 256) {
        int j = t & 127, sel = t >> 7;
        float s = 0.f;
        #pragma unroll
        for (int ww = 0; ww < 8; ++ww) s += red[sel * 1024 + ww * 128 + j];
        atomicAdd(&acc[sel * 128 + j], s);
    }
}

// ---- kernel 3: BN1 inline, sigmoid*relu; DEFERRED m-reduction ------------
// Main loop is barrier-free: per-thread register partials s0g/s1g per pair
// (g-loop fully unrolled so indices are compile-time — no scratch), then one
// LDS transpose (aliased over dead W3h) + fully parallel reduce.
__global__ __launch_bounds__(kT, 6)
void k_apply(const float* __restrict__ dist, const int* __restrict__ nbrs,
             const float* __restrict__ preA, const float* __restrict__ preB,
             const float* __restrict__ W3, const float* __restrict__ acc,
             const float* __restrict__ g1, const float* __restrict__ b1,
             float* __restrict__ summed, float* __restrict__ acc2) {
    __shared__ __align__(16) unsigned char smem[33792];  // W3h (loop) / red (tail)
    __shared__ float wv[kG][kM][kTaps];
    __shared__ int   roff[kG][kM];
    __shared__ int   wbase[kG][kM];
    __shared__ float scP[128], shP[128];
    half_t* W3h = (half_t*)smem;          // 25856 B live during main loop
    float*  red = (float*)smem;           // 32768 B live after main loop
    int t = threadIdx.x;
    int lb = (int)(blockIdx.x & 7) * (kNB / 8) + (int)(blockIdx.x >> 3);
    for (int i = t; i < kHB * kHO; i += kT)
        W3h[i] = (half_t)W3[(i & ~127) + origCh(i & 127)];
    if (t < kG * kM) {
        int g = t >> 5, m = t & 31;
        int p = lb * kG + g;
        float d = dist[p * kM + m];
        int kc = (int)floorf(d * 10.f);
        int ks = min(max(kc - 3, 0), kHB - kTaps);
        wbase[g][m] = ks * kHO;
        roff[g][m] = (((p >> 9) << 9) + nbrs[p * kM + m]) * kHO;
        #pragma unroll
        for (int j = 0; j < kTaps; ++j) {
            float dd = d - 0.1f * (float)(ks + j);
            wv[g][m][j] = __expf(-100.f * dd * dd);
        }
    }
    if (t < 128) {                         // BN1 scale/shift inline (perm order)
        float inv = 1.f / (float)kTRows;
        int oc = origCh(t);
        float mu = acc[t] * inv;
        float var = acc[128 + t] * inv - mu * mu;
        float sc = g1[oc] * rsqrtf(var + kEps);
        scP[t] = sc;
        shP[t] = b1[oc] - mu * sc;
    }
    __syncthreads();
    int cg = t & 31, ms = t >> 5;
    float4 sc4 = *(const float4*)&scP[4 * cg];
    float4 sh4 = *(const float4*)&shP[4 * cg];
    float s0g[kG], s1g[kG];
    #pragma unroll
    for (int g = 0; g < kG; ++g) { s0g[g] = 0.f; s1g[g] = 0.f; }
    #pragma unroll
    for (int g = 0; g < kG; ++g) {
        int p = lb * kG + g;
        float4 pa = *(const float4*)&preA[p * kHO + 4 * cg];
        #pragma unroll
        for (int mm = 0; mm < 2; ++mm) {
            int m = ms + mm * 16;
            int ro = roff[g][m], wb = wbase[g][m];
            float4 pb = *(const float4*)&preB[ro + 4 * cg];
            float x0 = pa.x + pb.x, x1 = pa.y + pb.y;
            float x2 = pa.z + pb.z, x3 = pa.w + pb.w;
            float warr[kTaps];
            *(float4*)&warr[0] = *(const float4*)&wv[g][m][0];
            *(float4*)&warr[4] = *(const float4*)&wv[g][m][4];
            const half_t* hb = &W3h[wb + 4 * cg];
            #pragma unroll
            for (int j = 0; j < kTaps; ++j) {
                half4 hv = *(const half4*)&hb[j * kHO];
                float w = warr[j];
                x0 = fmaf(w, (float)hv.x, x0);
                x1 = fmaf(w, (float)hv.y, x1);
                x2 = fmaf(w, (float)hv.z, x2);
                x3 = fmaf(w, (float)hv.w, x3);
            }
            float yf0 = fmaf(x0, sc4.x, sh4.x);
            float yc0 = fmaf(x1, sc4.y, sh4.y);
            float yf1 = fmaf(x2, sc4.z, sh4.z);
            float yc1 = fmaf(x3, sc4.w, sh4.w);
            float sg0 = 1.f / (1.f + __expf(-yf0));
            float sg1 = 1.f / (1.f + __expf(-yf1));
            s0g[g] = fmaf(sg0, fmaxf(yc0, 0.f), s0g[g]);
            s1g[g] = fmaf(sg1, fmaxf(yc1, 0.f), s1g[g]);
        }
    }
    __syncthreads();                       // W3h dead from here; reuse as red
    #pragma unroll
    for (int g = 0; g < kG; ++g)
        *(float2*)&red[(g * 16 + ms) * 64 + 2 * cg] = make_float2(s0g[g], s1g[g]);
    __syncthreads();
    int gg = t >> 6, ch = t & 63;          // 512 threads = 8 pairs x 64 channels
    float v = 0.f;
    #pragma unroll
    for (int m2 = 0; m2 < 16; ++m2) v += red[(gg * 16 + m2) * 64 + ch];
    summed[(size_t)(lb * kG + gg) * kHA + ch] = v;
    __syncthreads();
    red[t] = v;
    __syncthreads();
    if (t < 64) {
        float S2 = 0.f, SS2 = 0.f;
        #pragma unroll
        for (int g = 0; g < kG; ++g) {
            float u = red[g * 64 + t];
            S2 += u;
            SS2 = fmaf(u, u, SS2);
        }
        atomicAdd(&acc2[t], S2);
        atomicAdd(&acc2[64 + t], SS2);
    }
}

// ---- kernel F: inline BN2, resid + pool + classifier + softmax -----------
__global__ __launch_bounds__(1024)
void k_final(const float* __restrict__ atom, const float* __restrict__ summed,
             const float* __restrict__ acc2, const float* __restrict__ g2,
             const float* __restrict__ b2, const float* __restrict__ cw,
             const float* __restrict__ cb, float* __restrict__ out) {
    __shared__ float red[1024];
    __shared__ float sc2s[128];
    __shared__ float pooled[kHA];
    __shared__ float lg[kNCls];
    int b = blockIdx.x, t = threadIdx.x;
    if (t < 64) {
        float inv = 1.f / (float)kRows;
        float mu = acc2[t] * inv;
        float var = acc2[64 + t] * inv - mu * mu;
        float sc = g2[t] * rsqrtf(var + kEps);
        sc2s[t] = sc;
        sc2s[64 + t] = b2[t] - mu * sc;
    }
    __syncthreads();
    int h = t & 63, q = t >> 6;
    const float* ab = atom + (long)b * kN * kHA;
    const float* sb = summed + (long)b * kN * kHA;
    float scv = sc2s[h], shv = sc2s[64 + h];
    float s = 0.f;
    for (int n = q * 32; n < q * 32 + 32; ++n) {
        float v = ab[n * 64 + h] + fmaf(sb[n * 64 + h], scv, shv);
        s += fmaxf(v, 0.f);
    }
    red[t] = s;
    __syncthreads();
    if (t < 64) {
        float v = 0.f;
        #pragma unroll
        for (int qq = 0; qq < 16; ++qq) v += red[qq * 64 + t];
        pooled[t] = v * (1.f / kN);
    }
    __syncthreads();
    if (t < kNCls) {
        float a = cb[t];
        #pragma unroll
        for (int k = 0; k < kHA; ++k) a = fmaf(pooled[k], cw[k * kNCls + t], a);
        lg[t] = a;
    }
    __syncthreads();
    if (t == 0) {
        float mx = lg[0];
        for (int c = 1; c < kNCls; ++c) mx = fmaxf(mx, lg[c]);
        float e[kNCls], se = 0.f;
        for (int c = 0; c < kNCls; ++c) { e[c] = __expf(lg[c] - mx); se += e[c]; }
        float inv = 1.f / se;
        for (int c = 0; c < kNCls; ++c) out[b * kNCls + c] = e[c] * inv;
    }
}

// ---- launcher ------------------------------------------------------------
extern "C" void kernel_launch(void* const* d_in, const int* in_sizes, int n_in,
                              void* d_out, int out_size, void* d_ws, size_t ws_size,
                              hipStream_t stream) {
    const float* dist = (const float*)d_in[0];
    const int*   nbrs = (const int*)d_in[1];
    const float* emb  = (const float*)d_in[2];
    const float* fcw  = (const float*)d_in[3];
    const float* fcb  = (const float*)d_in[4];
    const float* bn1g = (const float*)d_in[5];
    const float* bn1b = (const float*)d_in[6];
    const float* bn2g = (const float*)d_in[7];
    const float* bn2b = (const float*)d_in[8];
    const float* clw  = (const float*)d_in[9];
    const float* clb  = (const float*)d_in[10];
    float* out = (float*)d_out;

    float* ws     = (float*)d_ws;
    float* atom   = ws;                          // kRows*kHA
    float* preA   = atom + kRows * kHA;          // kRows*kHO (perm)
    float* preB   = preA + kRows * kHO;          // kRows*kHO (perm)
    float* summed = preB + kRows * kHO;          // kRows*kHA
    float* bn1acc = summed + kRows * kHA;        // 256 (S perm | SS perm)
    float* acc2a  = bn1acc + 256;                // 128 (BN2 S|SS, even layers)
    float* acc2b  = acc2a + 128;                 // 128 (odd layers)

    k_init_atom<<<dim3(kRows * kHA / 256), dim3(256), 0, stream>>>(emb, atom);
    for (int l = 0; l < 4; ++l) {
        const float* W  = fcw + (long)l * kNF * kHO;
        const float* W3 = W + 2 * kHA * kHO;
        float* accW = (l & 1) ? acc2b : acc2a;
        float* accR = ((l - 1) & 1) ? acc2b : acc2a;
        if (l == 0)
            k_pre<false><<<dim3(kRows / 32), dim3(256), 0, stream>>>(
                atom, atom, nullptr, nullptr, nullptr, nullptr,
                W, fcb + l * kHO, preA, preB, bn1acc, accW);
        else
            k_pre<true><<<dim3(kRows / 32), dim3(256), 0, stream>>>(
                atom, atom, summed, accR, bn2g + (l - 1) * kHA, bn2b + (l - 1) * kHA,
                W, fcb + l * kHO, preA, preB, bn1acc, accW);
        k_stats<<<dim3(kNB), dim3(kT), 0, stream>>>(dist, nbrs, preA, preB, W3, bn1acc);
        k_apply<<<dim3(kNB), dim3(kT), 0, stream>>>(dist, nbrs, preA, preB, W3, bn1acc,
                                                    bn1g + l * kHO, bn1b + l * kHO,
                                                    summed, accW);
    }
    k_final<<<dim3(kB), dim3(1024), 0, stream>>>(atom, summed, acc2b,
                                                 bn2g + 3 * kHA, bn2b + 3 * kHA,
                                                 clw, clb, out);
}